// Round 1
// baseline (285.937 us; speedup 1.0000x reference)
//
#include <hip/hip_runtime.h>

// Masked attention B=8, NQ=1024, S=2048, D=512, fp32 in/out.
// prep: K -> Kf fp16, V -> Vt fp16 [b][d][s] (128B-segment transposed writes).
// attn_flash r9:
//   - sK DOUBLE-BUFFERED; K(i+1)+mask(i+1) issued right after B1 -> one full
//     tile of flight before the B1 DRAIN_ALL retires them (was: phase-B only).
//   - sV dropped. PV reads Vt from global (L2-resident via XCD swizzle) into
//     vb[8] registers, prefetched BEFORE B3 so L2 latency hides under the
//     barrier + stats merge. PV waves = 4 d-quarters x 2 q-rowtiles -> each V
//     row read once per WG (old layout read each row twice).
//   - B3 is a RAW s_barrier + lgkmcnt(0) (sP/stats visibility only); the K
//     DMA + mask stay in flight across it (no __syncthreads vmcnt(0) drain).
//   - XCD swizzle: bx=(bx&7)*64+(bx>>3) -> each XCD owns one b (4MB K+V in
//     its 4MB L2).
//   - EXACT defer-rescale: skip the 64-mul oacc rescale + 8 exps when the
//     running max didn't grow for any row this tile (alpha==1 exactly).
//   - P scaling in packed f16 (v_pk_mul_f16) instead of f32 round-trip.
//   LDS 70.1KB -> 2 WGs/CU; one vmcnt(0) drain per tile (B1, ~free now).
// combine: merge the 2 S-halves.

#define Bz 8
#define NQz 1024
#define Sz 2048
#define Dz 512
#define QT 32
#define TS 32
#define NT ((Sz / 2) / TS)
#define KP 520   // sK row pitch (f16 elems); 1040B rows
#define PP 40

typedef _Float16 f16x8 __attribute__((ext_vector_type(8)));
typedef float f32x4 __attribute__((ext_vector_type(4)));
typedef unsigned short ushort_t;

#define AS1(p) ((const __attribute__((address_space(1))) unsigned int*)(p))
#define AS3(p) ((__attribute__((address_space(3))) unsigned int*)(p))
#define DRAIN_ALL() __builtin_amdgcn_s_waitcnt(0)

__device__ __forceinline__ ushort_t f2h(float x) {
  _Float16 h = (_Float16)x;  // RNE
  return __builtin_bit_cast(ushort_t, h);
}
__device__ __forceinline__ float h2f(ushort_t u) {
  return (float)__builtin_bit_cast(_Float16, u);
}

// ---------------- prep: K -> fp16, V -> Vt fp16 transposed ----------------
__global__ __launch_bounds__(256)
void prep(const float* __restrict__ K, const float* __restrict__ V,
          ushort_t* __restrict__ Kf, ushort_t* __restrict__ Vt) {
  __shared__ ushort_t sT[64][41];
  const int t = threadIdx.x;
  int bx = blockIdx.x;
  if (bx < 8192) {
    size_t e = ((size_t)bx * 256 + t) * 4;
    float4 v = *(const float4*)(K + e);
    uint2 w;
    w.x = (unsigned)f2h(v.x) | ((unsigned)f2h(v.y) << 16);
    w.y = (unsigned)f2h(v.z) | ((unsigned)f2h(v.w) << 16);
    *(uint2*)(Kf + e) = w;
    return;
  }
  bx -= 8192;
  const int b = bx >> 9;
  const int rest = bx & 511;
  const int st = rest >> 4;   // 0..31, s-tiles of 64
  const int dt = rest & 15;   // 0..15, d-tiles of 32
  const int s0 = st * 64, d0 = dt * 32;
  const float* Vb = V + ((size_t)b * Sz + s0) * Dz + d0;
#pragma unroll
  for (int i = 0; i < 2; ++i) {
    int idx = t + 256 * i;    // 0..511
    int s = idx >> 3;         // 0..63
    int dc = (idx & 7) * 4;   // 0..28
    float4 v = *(const float4*)(Vb + (size_t)s * Dz + dc);
    uint2 w;
    w.x = (unsigned)f2h(v.x) | ((unsigned)f2h(v.y) << 16);
    w.y = (unsigned)f2h(v.z) | ((unsigned)f2h(v.w) << 16);
    *(uint2*)(&sT[s][dc]) = w;
  }
  __syncthreads();
  ushort_t* VtB = Vt + ((size_t)b * Dz + d0) * Sz + s0;
  {
    int d = t >> 3, c = t & 7;
    uint4 u;
    ushort_t* tp = (ushort_t*)&u;
#pragma unroll
    for (int j = 0; j < 8; ++j) tp[j] = sT[c * 8 + j][d];
    *(uint4*)(VtB + (size_t)d * Sz + c * 8) = u;  // 8 thr x 16B = 128B seg
  }
}

// ---------------- attention ----------------
__global__ __launch_bounds__(256, 2)
void attn_flash(const float* __restrict__ Q, const int* __restrict__ Msk,
                const ushort_t* __restrict__ Kf, const ushort_t* __restrict__ Vt,
                float* __restrict__ Opart, float* __restrict__ Mpart,
                float* __restrict__ Lpart) {
  __shared__ ushort_t sK[2][TS][KP];    // 66.6 KB (double-buffered)
  __shared__ ushort_t sP[QT][PP];       // 2.6 KB
  __shared__ float sTMax[2][QT];
  __shared__ float sTSum[2][QT];
  __shared__ float sM[2][QT];
  __shared__ float sL[2][QT];

  const int tid  = threadIdx.x;
  const int wave = tid >> 6;
  const int lane = tid & 63;
  const int l16  = lane & 15;
  const int quad = lane >> 4;
  const int rw   = wave & 1;   // QK: q row-tile of 16
  const int cw   = wave >> 1;  // QK: s col-half

  int bxr = blockIdx.x;
  const int bx = (bxr & 7) * 64 + (bxr >> 3);  // XCD swizzle: b == XCD
  const int b  = bx >> 6;
  const int r6 = bx & 63;
  const int qt = r6 >> 1;
  const int sh = r6 & 1;
  const int q0 = qt * QT;
  const int sbeg = sh * (Sz / 2);

  const float*    Qb  = Q  + ((size_t)b * NQz + q0) * Dz;
  const ushort_t* KfB = Kf + (size_t)b * Sz * Dz;
  const ushort_t* VtB = Vt + (size_t)b * Dz * Sz;
  const int*      Mb  = Msk + ((size_t)b * NQz + q0) * (size_t)Sz;

  auto issue_k = [&](int s0n, int bsel) {
#pragma unroll
    for (int j = 0; j < 8; ++j) {
      int row = wave * 8 + j;
      const ushort_t* gp = KfB + (size_t)(s0n + row) * Dz + lane * 8;
      __builtin_amdgcn_global_load_lds(AS1(gp), AS3(&sK[bsel][row][0]), 16, 0, 0);
    }
  };
  // S^T layout: lane l16 = q (within rw tile), quad*4+r = s (within cw half)
  auto load_mask = [&](int s0n) -> int4 {
    return *(const int4*)(Mb + (size_t)(rw * 16 + l16) * Sz + s0n +
                          cw * 16 + quad * 4);
  };

  // prologue: K(0) + mask(0) in flight before the heavy Q load
  issue_k(sbeg, 0);
  int4 msk_cur = load_mask(sbeg);

  // Q frags fp16 (rows rw*16+l16), register-resident; B operand of swapped QK.
  f16x8 qa[16];
  {
    const float* qrow = Qb + (size_t)(rw * 16 + l16) * Dz;
#pragma unroll
    for (int kk = 0; kk < 16; ++kk) {
      const float4 a = *(const float4*)(qrow + kk * 32 + quad * 8);
      const float4 c = *(const float4*)(qrow + kk * 32 + quad * 8 + 4);
      f16x8 h;
      h[0] = (_Float16)a.x; h[1] = (_Float16)a.y;
      h[2] = (_Float16)a.z; h[3] = (_Float16)a.w;
      h[4] = (_Float16)c.x; h[5] = (_Float16)c.y;
      h[6] = (_Float16)c.z; h[7] = (_Float16)c.w;
      qa[kk] = h;
    }
  }

  if (tid < QT) { sM[0][tid] = -1e30f; sL[0][tid] = 0.0f; }

  f32x4 oacc[16];
#pragma unroll
  for (int t = 0; t < 16; ++t) oacc[t] = (f32x4){0.f, 0.f, 0.f, 0.f};

  int p = 0;
  for (int i = 0; i < NT; ++i) {
    const int s0 = sbeg + i * TS;
    const int bsel = i & 1;

    DRAIN_ALL();      // retire K(i) DMA + mask(i) — both had a full tile in flight
    __syncthreads();  // B1: prev-tile sP readers done; stats swap visible

    int4 msk_nxt{0, 0, 0, 0};
    if (i + 1 < NT) {
      issue_k(s0 + TS, bsel ^ 1);   // full-tile flight, drained at B1(i+1)
      msk_nxt = load_mask(s0 + TS);
    }

    // ---- S^T = K·Q^T from sK[bsel]: dual accumulators ----
    f32x4 sc0 = (f32x4){0.f, 0.f, 0.f, 0.f};
    f32x4 sc1 = (f32x4){0.f, 0.f, 0.f, 0.f};
    {
      const ushort_t* kh = &sK[bsel][cw * 16 + l16][quad * 8];
#pragma unroll
      for (int kk = 0; kk < 16; kk += 2) {
        f16x8 b0 = *(const f16x8*)(kh + kk * 32);
        f16x8 b1 = *(const f16x8*)(kh + kk * 32 + 32);
        sc0 = __builtin_amdgcn_mfma_f32_16x16x32_f16(b0, qa[kk], sc0, 0, 0, 0);
        sc1 = __builtin_amdgcn_mfma_f32_16x16x32_f16(b1, qa[kk + 1], sc1, 0, 0, 0);
      }
    }
    f32x4 sc;
#pragma unroll
    for (int r = 0; r < 4; ++r) sc[r] = sc0[r] + sc1[r];

    // ---- phase A: mask, per-half max + expsum ----
    int msk_r[4] = {msk_cur.x, msk_cur.y, msk_cur.z, msk_cur.w};
    float se[4];
#pragma unroll
    for (int r = 0; r < 4; ++r) se[r] = msk_r[r] ? sc[r] : -1e30f;
    float rmax = fmaxf(fmaxf(se[0], se[1]), fmaxf(se[2], se[3]));
    rmax = fmaxf(rmax, __shfl_xor(rmax, 16));
    rmax = fmaxf(rmax, __shfl_xor(rmax, 32));
    ushort_t pb[4];
    float rsum = 0.f;
#pragma unroll
    for (int r = 0; r < 4; ++r) {
      float pv = msk_r[r] ? __expf(se[r] - rmax) : 0.0f;
      pb[r] = f2h(pv);
      rsum += h2f(pb[r]);
    }
    {
      uint2 w;
      w.x = (unsigned)pb[0] | ((unsigned)pb[1] << 16);
      w.y = (unsigned)pb[2] | ((unsigned)pb[3] << 16);
      *(uint2*)(&sP[rw * 16 + l16][cw * 16 + quad * 4]) = w;
    }
    rsum += __shfl_xor(rsum, 16);
    rsum += __shfl_xor(rsum, 32);
    if (quad == 0) {
      sTMax[cw][rw * 16 + l16] = rmax;
      sTSum[cw][rw * 16 + l16] = rsum;
    }

    // ---- V prefetch (this tile) from global/L2 into regs; wave = d-quarter;
    // each V row read ONCE per WG; hides L2 latency under B3 + stats ----
    f16x8 vb[8];
#pragma unroll
    for (int dt = 0; dt < 8; ++dt) {
      vb[dt] = *(const f16x8*)(VtB +
          (size_t)(wave * 128 + dt * 16 + l16) * Sz + s0 + quad * 8);
    }

    // B3 (raw): sP + stats visibility only. K(i+1) DMA + mask stay in flight.
    asm volatile("s_waitcnt lgkmcnt(0)" ::: "memory");
    __builtin_amdgcn_s_barrier();
    asm volatile("" ::: "memory");

    // ---- phase B: merge stats (defer-rescale), packed-f16 P scale, PV ----
    const int pr = p;
    f16x8 pa[2];
#pragma unroll
    for (int rt = 0; rt < 2; ++rt) {
      const int row16 = rt * 16 + l16;
      float t0v = sTMax[0][row16], t1v = sTMax[1][row16];
      float mo16 = sM[pr][row16];
      float mn16 = fmaxf(mo16, fmaxf(t0v, t1v));
      float scl = __expf(((quad >> 1) ? t1v : t0v) - mn16);
      f16x8 praw = *(const f16x8*)(&sP[row16][quad * 8]);
      _Float16 sh16 = (_Float16)scl;
#pragma unroll
      for (int j = 0; j < 8; ++j) pa[rt][j] = praw[j] * sh16;  // v_pk_mul_f16
    }

    float dd[2][4];
    bool grow = false;
#pragma unroll
    for (int rt = 0; rt < 2; ++rt) {
#pragma unroll
      for (int r = 0; r < 4; ++r) {
        const int rc = rt * 16 + quad * 4 + r;
        float a0 = sTMax[0][rc], a1 = sTMax[1][rc];
        float mo = sM[pr][rc];
        float mn = fmaxf(mo, fmaxf(a0, a1));
        dd[rt][r] = mo - mn;
        grow = grow || (mn > mo);
        if (wave == 0 && l16 == 0) {  // wave 0 owns all 32 rows' stats
          sM[pr ^ 1][rc] = mn;
          sL[pr ^ 1][rc] = __expf(mo - mn) * sL[pr][rc]
                         + __expf(a0 - mn) * sTSum[0][rc]
                         + __expf(a1 - mn) * sTSum[1][rc];
        }
      }
    }
    if (__any((int)grow)) {  // EXACT skip: alpha==1 for every row when !grow
      float al[2][4];
#pragma unroll
      for (int rt = 0; rt < 2; ++rt)
#pragma unroll
        for (int r = 0; r < 4; ++r) al[rt][r] = __expf(dd[rt][r]);
#pragma unroll
      for (int t = 0; t < 16; ++t)
#pragma unroll
        for (int r = 0; r < 4; ++r) oacc[t][r] *= al[t >> 3][r];
    }

    // PV: oacc[rt*8+dt] covers rows rt*16.., cols wave*128 + dt*16 + l16
#pragma unroll
    for (int dt = 0; dt < 8; ++dt) {
#pragma unroll
      for (int rt = 0; rt < 2; ++rt) {
        oacc[rt * 8 + dt] = __builtin_amdgcn_mfma_f32_16x16x32_f16(
            pa[rt], vb[dt], oacc[rt * 8 + dt], 0, 0, 0);
      }
    }

    msk_cur = msk_nxt;
    p ^= 1;
  }

  DRAIN_ALL();
  __syncthreads();  // final sM/sL (buffer p) visible
  const size_t rbase = (size_t)(b * 2 + sh) * NQz + q0;
#pragma unroll
  for (int t = 0; t < 16; ++t) {
#pragma unroll
    for (int r = 0; r < 4; ++r) {
      int rowq = (t >> 3) * 16 + quad * 4 + r;
      Opart[(rbase + rowq) * Dz + wave * 128 + (t & 7) * 16 + l16] = oacc[t][r];
    }
  }
  if (tid < QT) {
    Mpart[rbase + tid] = sM[p][tid];
    Lpart[rbase + tid] = sL[p][tid];
  }
}

// ---------------- combine the two S-halves ----------------
__global__ __launch_bounds__(256)
void combine(const float* __restrict__ Opart, const float* __restrict__ Mpart,
             const float* __restrict__ Lpart, float* __restrict__ Out) {
  int gid = blockIdx.x * 256 + threadIdx.x;
  int row = gid >> 7;
  int b   = row >> 10;
  int q   = row & 1023;
  int c   = (gid & 127) * 4;
  size_t i0 = (size_t)(b * 2 + 0) * NQz + q;
  size_t i1 = (size_t)(b * 2 + 1) * NQz + q;
  float m0 = Mpart[i0], m1 = Mpart[i1];
  float l0 = Lpart[i0], l1 = Lpart[i1];
  float m  = fmaxf(m0, m1);
  float w0 = __expf(m0 - m), w1 = __expf(m1 - m);
  float inv = 1.0f / (w0 * l0 + w1 * l1);
  float4 a = *(const float4*)(Opart + i0 * Dz + c);
  float4 bv = *(const float4*)(Opart + i1 * Dz + c);
  float4 o;
  o.x = (w0 * a.x + w1 * bv.x) * inv;
  o.y = (w0 * a.y + w1 * bv.y) * inv;
  o.z = (w0 * a.z + w1 * bv.z) * inv;
  o.w = (w0 * a.w + w1 * bv.w) * inv;
  *(float4*)(Out + ((size_t)b * NQz + q) * Dz + c) = o;
}

extern "C" void kernel_launch(void* const* d_in, const int* in_sizes, int n_in,
                              void* d_out, int out_size, void* d_ws, size_t ws_size,
                              hipStream_t stream) {
  const float* Q = (const float*)d_in[0];
  const float* K = (const float*)d_in[1];
  const float* V = (const float*)d_in[2];
  const int*   M = (const int*)d_in[3];
  float* O = (float*)d_out;

  const size_t NKV = (size_t)Bz * Sz * Dz;
  ushort_t* Kf = (ushort_t*)d_ws;
  ushort_t* Vt = Kf + NKV;
  float* Opart = (float*)(Vt + NKV);
  float* Mpart = Opart + (size_t)Bz * 2 * NQz * Dz;
  float* Lpart = Mpart + (size_t)Bz * 2 * NQz;

  prep<<<dim3(12288), dim3(256), 0, stream>>>(K, V, Kf, Vt);
  attn_flash<<<dim3(512), dim3(256), 0, stream>>>(Q, M, Kf, Vt, Opart, Mpart, Lpart);
  combine<<<dim3(4096), dim3(256), 0, stream>>>(Opart, Mpart, Lpart, O);
}

// Round 2
// 265.490 us; speedup vs baseline: 1.0770x; 1.0770x over previous
//
#include <hip/hip_runtime.h>

// Masked attention B=8, NQ=1024, S=2048, D=512, fp32 in/out.
// prep: K -> Kf fp16; V -> Vt fp16 [b][d][s] (128B-segment transposed writes);
//       mask int32 -> bit-packed Mp (64MB -> 2MB, so attn reads mask from L2).
// attn_flash r10 = r8 schedule (117us measured) + orthogonal wins:
//   - r8 DMA schedule RESTORED: sV via LDS-DMA issued post-B1 (drained at B3,
//     flight = QK+phaseA); K(i+1)+mask(i+1) issued post-B3 (drained at B1,
//     flight = phaseB). r9's register-V + early-K variant put a vmcnt drain
//     mid-phase-B (in-order vmcnt: waiting on newest V regs drained the K DMA
//     too) and scattered V reads -> reverted.
//   - mask = one uint32 bitfield per lane per tile (L2), not int4 from HBM.
//   - XCD swizzle: bx=(bx&7)*64+(bx>>3) -> each XCD owns one b; Kf+Vt half
//     (4MB) lives in its 4MB L2 (proven: FETCH_SIZE halved in r9).
//   - EXACT defer-rescale (skip 64-mul oacc rescale when no row's max grew)
//     + packed-f16 P scaling.
//   LDS ~70KB -> 2 WGs/CU; 4-wave WGs; QT=32, TS=32, S-split=2 -> 512 WGs.
// combine: merge the 2 S-halves.

#define Bz 8
#define NQz 1024
#define Sz 2048
#define Dz 512
#define QT 32
#define TS 32
#define NT ((Sz / 2) / TS)
#define KP 520   // sK row pitch (f16 elems); 1040B rows
#define PP 40

typedef _Float16 f16x8 __attribute__((ext_vector_type(8)));
typedef float f32x4 __attribute__((ext_vector_type(4)));
typedef unsigned short ushort_t;

#define AS1(p) ((const __attribute__((address_space(1))) unsigned int*)(p))
#define AS3(p) ((__attribute__((address_space(3))) unsigned int*)(p))
#define DRAIN_ALL() __builtin_amdgcn_s_waitcnt(0)

__device__ __forceinline__ ushort_t f2h(float x) {
  _Float16 h = (_Float16)x;  // RNE
  return __builtin_bit_cast(ushort_t, h);
}
__device__ __forceinline__ float h2f(ushort_t u) {
  return (float)__builtin_bit_cast(_Float16, u);
}

// ---- prep: K -> fp16 | V -> Vt fp16 transposed | mask -> bitpack ----
__global__ __launch_bounds__(256)
void prep(const float* __restrict__ K, const float* __restrict__ V,
          const int* __restrict__ Mi, ushort_t* __restrict__ Kf,
          ushort_t* __restrict__ Vt, unsigned* __restrict__ Mp) {
  __shared__ ushort_t sT[64][41];
  const int t = threadIdx.x;
  int bx = blockIdx.x;
  if (bx < 8192) {  // K fp32 -> fp16, fully coalesced
    size_t e = ((size_t)bx * 256 + t) * 4;
    float4 v = *(const float4*)(K + e);
    uint2 w;
    w.x = (unsigned)f2h(v.x) | ((unsigned)f2h(v.y) << 16);
    w.y = (unsigned)f2h(v.z) | ((unsigned)f2h(v.w) << 16);
    *(uint2*)(Kf + e) = w;
    return;
  }
  bx -= 8192;
  if (bx < 4096) {  // V transpose, 64s x 32d tiles, 128B write segments
    const int b = bx >> 9;
    const int rest = bx & 511;
    const int st = rest >> 4;   // 0..31, s-tiles of 64
    const int dt = rest & 15;   // 0..15, d-tiles of 32
    const int s0 = st * 64, d0 = dt * 32;
    const float* Vb = V + ((size_t)b * Sz + s0) * Dz + d0;
#pragma unroll
    for (int i = 0; i < 2; ++i) {
      int idx = t + 256 * i;    // 0..511
      int s = idx >> 3;         // 0..63
      int dc = (idx & 7) * 4;   // 0..28
      float4 v = *(const float4*)(Vb + (size_t)s * Dz + dc);
      uint2 w;
      w.x = (unsigned)f2h(v.x) | ((unsigned)f2h(v.y) << 16);
      w.y = (unsigned)f2h(v.z) | ((unsigned)f2h(v.w) << 16);
      *(uint2*)(&sT[s][dc]) = w;
    }
    __syncthreads();
    ushort_t* VtB = Vt + ((size_t)b * Dz + d0) * Sz + s0;
    int d = t >> 3, c = t & 7;
    uint4 u;
    ushort_t* tp = (ushort_t*)&u;
#pragma unroll
    for (int j = 0; j < 8; ++j) tp[j] = sT[c * 8 + j][d];
    *(uint4*)(VtB + (size_t)d * Sz + c * 8) = u;  // 8 thr x 16B = 128B seg
    return;
  }
  bx -= 4096;  // mask bitpack: 1024 ints/block, coalesced int4 + shuffle-or
  const int lane = t & 63;
  const size_t base = (size_t)bx * 1024 + t * 4;
  const int4 mv = *(const int4*)(Mi + base);
  unsigned nib = (mv.x ? 1u : 0u) | (mv.y ? 2u : 0u) |
                 (mv.z ? 4u : 0u) | (mv.w ? 8u : 0u);
  unsigned v = nib << ((lane & 7) * 4);
  v |= __shfl_xor(v, 1);
  v |= __shfl_xor(v, 2);
  v |= __shfl_xor(v, 4);
  if ((lane & 7) == 0) Mp[bx * 32 + (t >> 3)] = v;  // bit i of word w = mask[32w+i]
}

// ---------------- attention ----------------
__global__ __launch_bounds__(256, 2)
void attn_flash(const float* __restrict__ Q, const unsigned* __restrict__ Mp,
                const ushort_t* __restrict__ Kf, const ushort_t* __restrict__ Vt,
                float* __restrict__ Opart, float* __restrict__ Mpart,
                float* __restrict__ Lpart) {
  __shared__ ushort_t sK[TS][KP];       // 33.3 KB
  __shared__ ushort_t sV[Dz][TS];       // 32.8 KB (64B rows, DMA-contiguous)
  __shared__ ushort_t sP[QT][PP];       // 2.6 KB
  __shared__ float sTMax[2][QT];
  __shared__ float sTSum[2][QT];
  __shared__ float sM[2][QT];
  __shared__ float sL[2][QT];

  const int tid  = threadIdx.x;
  const int wave = tid >> 6;
  const int lane = tid & 63;
  const int l16  = lane & 15;
  const int quad = lane >> 4;
  const int rw   = wave & 1;   // q row-tile of 16
  const int cw   = wave >> 1;  // s col-half (QK) / d half (PV)

  int bxr = blockIdx.x;
  const int bx = (bxr & 7) * 64 + (bxr >> 3);  // XCD swizzle: b == XCD
  const int b  = bx >> 6;
  const int r6 = bx & 63;
  const int qt = r6 >> 1;
  const int sh = r6 & 1;
  const int q0 = qt * QT;
  const int sbeg = sh * (Sz / 2);

  const float*    Qb  = Q  + ((size_t)b * NQz + q0) * Dz;
  const ushort_t* KfB = Kf + (size_t)b * Sz * Dz;
  const ushort_t* VtB = Vt + (size_t)b * Dz * Sz;
  const unsigned* MpB = Mp + ((size_t)b * NQz + q0) * (Sz / 32);

  auto issue_k = [&](int s0n) {
#pragma unroll
    for (int j = 0; j < 8; ++j) {
      int row = wave * 8 + j;
      const ushort_t* gp = KfB + (size_t)(s0n + row) * Dz + lane * 8;
      __builtin_amdgcn_global_load_lds(AS1(gp), AS3(&sK[row][0]), 16, 0, 0);
    }
  };
  auto issue_v = [&](int s0n) {
#pragma unroll
    for (int j = 0; j < 8; ++j) {
      int dbase = wave * 128 + j * 16;
      const ushort_t* gp =
          VtB + (size_t)(dbase + (lane >> 2)) * Sz + s0n + (lane & 3) * 8;
      __builtin_amdgcn_global_load_lds(AS1(gp), AS3(&sV[dbase][0]), 16, 0, 0);
    }
  };
  // S^T layout: lane l16 = q (within rw tile), quad*4+r = s (within cw half).
  // One packed word covers this lane's 32 s-bits of its q-row for the tile.
  auto load_mask = [&](int s0n) -> unsigned {
    return MpB[(size_t)(rw * 16 + l16) * (Sz / 32) + (s0n >> 5)];
  };

  // prologue: K(0) + mask(0) in flight before the heavy Q load
  issue_k(sbeg);
  unsigned msk_cur = load_mask(sbeg);

  // Q frags fp16 (rows rw*16+l16), register-resident; B operand of swapped QK.
  f16x8 qa[16];
  {
    const float* qrow = Qb + (size_t)(rw * 16 + l16) * Dz;
#pragma unroll
    for (int kk = 0; kk < 16; ++kk) {
      const float4 a = *(const float4*)(qrow + kk * 32 + quad * 8);
      const float4 c = *(const float4*)(qrow + kk * 32 + quad * 8 + 4);
      f16x8 h;
      h[0] = (_Float16)a.x; h[1] = (_Float16)a.y;
      h[2] = (_Float16)a.z; h[3] = (_Float16)a.w;
      h[4] = (_Float16)c.x; h[5] = (_Float16)c.y;
      h[6] = (_Float16)c.z; h[7] = (_Float16)c.w;
      qa[kk] = h;
    }
  }

  if (tid < QT) { sM[0][tid] = -1e30f; sL[0][tid] = 0.0f; }

  f32x4 oacc[16];
#pragma unroll
  for (int t = 0; t < 16; ++t) oacc[t] = (f32x4){0.f, 0.f, 0.f, 0.f};

  int p = 0;
  for (int i = 0; i < NT; ++i) {
    const int s0 = sbeg + i * TS;
    const int sNext = (i + 1 < NT) ? s0 + TS : sbeg;  // wraps; junk unread

    DRAIN_ALL();      // K(i) DMA + mask retired before anyone crosses B1
    __syncthreads();  // B1: phase-B(i-1) sV/sP reads done

    issue_v(s0);  // V(i): overlaps QK+phaseA, drained at B3(i), read phase B(i)

    // ---- S^T = K·Q^T: dual accumulators halve the serial MFMA chain ----
    f32x4 sc0 = (f32x4){0.f, 0.f, 0.f, 0.f};
    f32x4 sc1 = (f32x4){0.f, 0.f, 0.f, 0.f};
    {
      const ushort_t* kh = &sK[cw * 16 + l16][quad * 8];
#pragma unroll
      for (int kk = 0; kk < 16; kk += 2) {
        f16x8 b0 = *(const f16x8*)(kh + kk * 32);
        f16x8 b1 = *(const f16x8*)(kh + kk * 32 + 32);
        sc0 = __builtin_amdgcn_mfma_f32_16x16x32_f16(b0, qa[kk], sc0, 0, 0, 0);
        sc1 = __builtin_amdgcn_mfma_f32_16x16x32_f16(b1, qa[kk + 1], sc1, 0, 0, 0);
      }
    }
    f32x4 sc;
#pragma unroll
    for (int r = 0; r < 4; ++r) sc[r] = sc0[r] + sc1[r];

    // ---- phase A: mask (bitfield), per-half max + expsum ----
    const unsigned mbits = msk_cur >> (cw * 16 + quad * 4);
    float se[4];
#pragma unroll
    for (int r = 0; r < 4; ++r) se[r] = ((mbits >> r) & 1u) ? sc[r] : -1e30f;
    float rmax = fmaxf(fmaxf(se[0], se[1]), fmaxf(se[2], se[3]));
    rmax = fmaxf(rmax, __shfl_xor(rmax, 16));
    rmax = fmaxf(rmax, __shfl_xor(rmax, 32));
    ushort_t pb[4];
    float rsum = 0.f;
#pragma unroll
    for (int r = 0; r < 4; ++r) {
      float pv = ((mbits >> r) & 1u) ? __expf(se[r] - rmax) : 0.0f;
      pb[r] = f2h(pv);
      rsum += h2f(pb[r]);
    }
    {  // one ds_write_b64: sP[q][cw*16+quad*4 .. +4)
      uint2 w;
      w.x = (unsigned)pb[0] | ((unsigned)pb[1] << 16);
      w.y = (unsigned)pb[2] | ((unsigned)pb[3] << 16);
      *(uint2*)(&sP[rw * 16 + l16][cw * 16 + quad * 4]) = w;
    }
    rsum += __shfl_xor(rsum, 16);
    rsum += __shfl_xor(rsum, 32);
    if (quad == 0) {
      sTMax[cw][rw * 16 + l16] = rmax;
      sTSum[cw][rw * 16 + l16] = rsum;
    }

    DRAIN_ALL();      // V(i) DMA retired before anyone crosses B3
    __syncthreads();  // B3: P + stats visible

    issue_k(sNext);              // K(i+1): drained at B1(i+1), flight = phase B
    unsigned msk_nxt = load_mask(sNext);  // consumed next phase A

    // ---- phase B: merge stats (defer-rescale), pk-f16 P scale, PV ----
    const int pr = p;
    f16x8 pa;
    {
      const int row16 = rw * 16 + l16;
      float t0v = sTMax[0][row16], t1v = sTMax[1][row16];
      float mo16 = sM[pr][row16];
      float mn16 = fmaxf(mo16, fmaxf(t0v, t1v));
      float scl = __expf(((quad >> 1) ? t1v : t0v) - mn16);
      f16x8 praw = *(const f16x8*)(&sP[row16][quad * 8]);
      _Float16 sh16 = (_Float16)scl;
#pragma unroll
      for (int j = 0; j < 8; ++j) pa[j] = praw[j] * sh16;  // v_pk_mul_f16
    }

    float dd[4];
    bool grow = false;
#pragma unroll
    for (int r = 0; r < 4; ++r) {
      const int rc = rw * 16 + quad * 4 + r;
      float a0 = sTMax[0][rc], a1 = sTMax[1][rc];
      float mo = sM[pr][rc];
      float mn = fmaxf(mo, fmaxf(a0, a1));
      dd[r] = mo - mn;
      grow = grow || (mn > mo);
      if (cw == 0 && l16 == 0) {
        sM[pr ^ 1][rc] = mn;
        sL[pr ^ 1][rc] = __expf(mo - mn) * sL[pr][rc]
                       + __expf(a0 - mn) * sTSum[0][rc]
                       + __expf(a1 - mn) * sTSum[1][rc];
      }
    }
    if (__any((int)grow)) {  // EXACT skip: alpha==1 for every row when !grow
      float al[4];
#pragma unroll
      for (int r = 0; r < 4; ++r) al[r] = __expf(dd[r]);
#pragma unroll
      for (int t = 0; t < 16; ++t)
#pragma unroll
        for (int r = 0; r < 4; ++r) oacc[t][r] *= al[r];
    }

#pragma unroll
    for (int t = 0; t < 16; ++t) {
      f16x8 vb = *(const f16x8*)(&sV[cw * 256 + t * 16 + l16][quad * 8]);
      oacc[t] = __builtin_amdgcn_mfma_f32_16x16x32_f16(pa, vb, oacc[t], 0, 0, 0);
    }

    msk_cur = msk_nxt;
    p ^= 1;
  }

  DRAIN_ALL();      // retire the wasted tail K-DMA before the final barrier
  __syncthreads();  // final sM/sL (buffer p) visible
  const size_t rbase = (size_t)(b * 2 + sh) * NQz + q0;
#pragma unroll
  for (int t = 0; t < 16; ++t) {
#pragma unroll
    for (int r = 0; r < 4; ++r) {
      int rowq = rw * 16 + quad * 4 + r;
      Opart[(rbase + rowq) * Dz + cw * 256 + t * 16 + l16] = oacc[t][r];
    }
  }
  if (tid < QT) {
    Mpart[rbase + tid] = sM[p][tid];
    Lpart[rbase + tid] = sL[p][tid];
  }
}

// ---------------- combine the two S-halves ----------------
__global__ __launch_bounds__(256)
void combine(const float* __restrict__ Opart, const float* __restrict__ Mpart,
             const float* __restrict__ Lpart, float* __restrict__ Out) {
  int gid = blockIdx.x * 256 + threadIdx.x;
  int row = gid >> 7;
  int b   = row >> 10;
  int q   = row & 1023;
  int c   = (gid & 127) * 4;
  size_t i0 = (size_t)(b * 2 + 0) * NQz + q;
  size_t i1 = (size_t)(b * 2 + 1) * NQz + q;
  float m0 = Mpart[i0], m1 = Mpart[i1];
  float l0 = Lpart[i0], l1 = Lpart[i1];
  float m  = fmaxf(m0, m1);
  float w0 = __expf(m0 - m), w1 = __expf(m1 - m);
  float inv = 1.0f / (w0 * l0 + w1 * l1);
  float4 a = *(const float4*)(Opart + i0 * Dz + c);
  float4 bv = *(const float4*)(Opart + i1 * Dz + c);
  float4 o;
  o.x = (w0 * a.x + w1 * bv.x) * inv;
  o.y = (w0 * a.y + w1 * bv.y) * inv;
  o.z = (w0 * a.z + w1 * bv.z) * inv;
  o.w = (w0 * a.w + w1 * bv.w) * inv;
  *(float4*)(Out + ((size_t)b * NQz + q) * Dz + c) = o;
}

extern "C" void kernel_launch(void* const* d_in, const int* in_sizes, int n_in,
                              void* d_out, int out_size, void* d_ws, size_t ws_size,
                              hipStream_t stream) {
  const float* Q = (const float*)d_in[0];
  const float* K = (const float*)d_in[1];
  const float* V = (const float*)d_in[2];
  const int*   M = (const int*)d_in[3];
  float* O = (float*)d_out;

  const size_t NKV = (size_t)Bz * Sz * Dz;
  ushort_t* Kf = (ushort_t*)d_ws;
  ushort_t* Vt = Kf + NKV;
  float* Opart = (float*)(Vt + NKV);
  float* Mpart = Opart + (size_t)Bz * 2 * NQz * Dz;
  float* Lpart = Mpart + (size_t)Bz * 2 * NQz;
  unsigned* Mp = (unsigned*)(Lpart + (size_t)Bz * 2 * NQz);  // 2MB bitmask

  // 8192 K-convert + 4096 V-transpose + 16384 mask-pack blocks
  prep<<<dim3(28672), dim3(256), 0, stream>>>(K, V, M, Kf, Vt, Mp);
  attn_flash<<<dim3(512), dim3(256), 0, stream>>>(Q, Mp, Kf, Vt, Opart, Mpart, Lpart);
  combine<<<dim3(4096), dim3(256), 0, stream>>>(Opart, Mpart, Lpart, O);
}

// Round 4
// 246.679 us; speedup vs baseline: 1.1591x; 1.0763x over previous
//
#include <hip/hip_runtime.h>

// Masked attention B=8, NQ=1024, S=2048, D=512, fp32 in/out.
// prep: K -> Kf fp16; V -> Vt fp16 [b][d][s]; mask -> bit-packed Mp (2MB).
// attn_flash r12 (= r11 intent, host fixed): WAVE-INDEPENDENT tiles.
//   - 512-thr WGs, 8 waves; wave w owns q-rows w*16..+15 END-TO-END:
//     full 32-s QK (4 indep MFMA chains), intra-wave softmax (shfl_xor),
//     intra-wave P exchange via private per-wave sP strip (wave-synchronous
//     LDS, NO barrier), full 512-d PV (32 MFMAs into 128-reg oacc).
//   - sK AND sV double-buffered (142KB LDS, 1 WG/CU = 256 WGs): ONE
//     drain+barrier per tile; DMA(i+1) has a FULL tile of flight.
//   - sV XOR-swizzle (16B slot ^= (d>>1)&3) via pre-swizzled DMA *source*
//     (dest linear, required by global_load_lds); PV ds_read_b128 8-way -> 2-way.
//   - stats m,l register-resident; EXACT defer-rescale skip.
//   - Opart stored fp16 -> split=4 fits the same ~69.5MB workspace r10 used.
//   HOST FIX vs r11: Mp offset is split-independent; SINGLE prep launch with
//   a real Mp pointer (r11 crashed writing through Mp=nullptr).
// combine: merge the SPLIT S-parts (fp16 Opart).

#define Bz 8
#define NQz 1024
#define Sz 2048
#define Dz 512
#define QTT 128   // q rows per WG (8 waves x 16)
#define TS 32
#define KP 520    // sK row pitch (f16); 1040B rows
#define PP 40     // sP row pitch (f16)

typedef _Float16 f16x8 __attribute__((ext_vector_type(8)));
typedef float f32x4 __attribute__((ext_vector_type(4)));
typedef unsigned short ushort_t;

#define AS1(p) ((const __attribute__((address_space(1))) unsigned int*)(p))
#define AS3(p) ((__attribute__((address_space(3))) unsigned int*)(p))
#define DRAIN_ALL() __builtin_amdgcn_s_waitcnt(0)

__device__ __forceinline__ ushort_t f2h(float x) {
  _Float16 h = (_Float16)x;  // RNE
  return __builtin_bit_cast(ushort_t, h);
}
__device__ __forceinline__ float h2f(ushort_t u) {
  return (float)__builtin_bit_cast(_Float16, u);
}

// ---- prep: K -> fp16 | V -> Vt fp16 transposed | mask -> bitpack ----
__global__ __launch_bounds__(256)
void prep(const float* __restrict__ K, const float* __restrict__ V,
          const int* __restrict__ Mi, ushort_t* __restrict__ Kf,
          ushort_t* __restrict__ Vt, unsigned* __restrict__ Mp) {
  __shared__ ushort_t sT[64][41];
  const int t = threadIdx.x;
  int bx = blockIdx.x;
  if (bx < 8192) {  // K fp32 -> fp16, fully coalesced
    size_t e = ((size_t)bx * 256 + t) * 4;
    float4 v = *(const float4*)(K + e);
    uint2 w;
    w.x = (unsigned)f2h(v.x) | ((unsigned)f2h(v.y) << 16);
    w.y = (unsigned)f2h(v.z) | ((unsigned)f2h(v.w) << 16);
    *(uint2*)(Kf + e) = w;
    return;
  }
  bx -= 8192;
  if (bx < 4096) {  // V transpose, 64s x 32d tiles, 128B write segments
    const int b = bx >> 9;
    const int rest = bx & 511;
    const int st = rest >> 4;
    const int dt = rest & 15;
    const int s0 = st * 64, d0 = dt * 32;
    const float* Vb = V + ((size_t)b * Sz + s0) * Dz + d0;
#pragma unroll
    for (int i = 0; i < 2; ++i) {
      int idx = t + 256 * i;
      int s = idx >> 3;
      int dc = (idx & 7) * 4;
      float4 v = *(const float4*)(Vb + (size_t)s * Dz + dc);
      uint2 w;
      w.x = (unsigned)f2h(v.x) | ((unsigned)f2h(v.y) << 16);
      w.y = (unsigned)f2h(v.z) | ((unsigned)f2h(v.w) << 16);
      *(uint2*)(&sT[s][dc]) = w;
    }
    __syncthreads();
    ushort_t* VtB = Vt + ((size_t)b * Dz + d0) * Sz + s0;
    int d = t >> 3, c = t & 7;
    uint4 u;
    ushort_t* tp = (ushort_t*)&u;
#pragma unroll
    for (int j = 0; j < 8; ++j) tp[j] = sT[c * 8 + j][d];
    *(uint4*)(VtB + (size_t)d * Sz + c * 8) = u;
    return;
  }
  bx -= 4096;  // mask bitpack: 1024 ints/block -> 32 words
  const int lane = t & 63;
  const size_t base = (size_t)bx * 1024 + t * 4;
  const int4 mv = *(const int4*)(Mi + base);
  unsigned nib = (mv.x ? 1u : 0u) | (mv.y ? 2u : 0u) |
                 (mv.z ? 4u : 0u) | (mv.w ? 8u : 0u);
  unsigned v = nib << ((lane & 7) * 4);
  v |= __shfl_xor(v, 1);
  v |= __shfl_xor(v, 2);
  v |= __shfl_xor(v, 4);
  if ((lane & 7) == 0) Mp[bx * 32 + (t >> 3)] = v;  // bit i of word w = mask[32w+i]
}

// ---------------- attention ----------------
template <int SPLIT>
__global__ __launch_bounds__(512, 2)
void attn_flash(const float* __restrict__ Q, const unsigned* __restrict__ Mp,
                const ushort_t* __restrict__ Kf, const ushort_t* __restrict__ Vt,
                ushort_t* __restrict__ Opart, float* __restrict__ Mpart,
                float* __restrict__ Lpart) {
  __shared__ ushort_t sK[2][TS][KP];    // 66.56 KB
  __shared__ ushort_t sV[2][Dz][TS];    // 65.54 KB (16B-slot XOR-swizzled)
  __shared__ ushort_t sP[8][16][PP];    // 10.24 KB, per-wave private strips

  const int tid  = threadIdx.x;
  const int wave = tid >> 6;
  const int lane = tid & 63;
  const int l16  = lane & 15;
  const int quad = lane >> 4;

  const int bxr = blockIdx.x;
  const int b   = bxr & 7;               // XCD swizzle: b == XCD
  const int rest = bxr >> 3;
  const int qt  = rest / SPLIT;
  const int sh  = rest % SPLIT;
  const int q0  = qt * QTT;
  const int SLEN = Sz / SPLIT;
  const int NTt  = SLEN / TS;
  const int sbeg = sh * SLEN;
  const int qw   = q0 + wave * 16;       // this wave's q base

  const float*    Qb  = Q  + ((size_t)b * NQz + qw) * Dz;
  const ushort_t* KfB = Kf + (size_t)b * Sz * Dz;
  const ushort_t* VtB = Vt + (size_t)b * Dz * Sz;
  const unsigned* MpB = Mp + ((size_t)b * NQz + qw) * (Sz / 32);

  // sV swizzle: physical 16B slot = logical_quad ^ ((d>>1)&3).
  const int vql  = (lane & 3) ^ ((lane >> 3) & 3);   // DMA source slot
  const int vcol = (quad ^ ((l16 >> 1) & 3)) * 8;    // read slot (f16 elems)

  auto issue_tile = [&](int s0n, int bsel) {
#pragma unroll
    for (int j = 0; j < 4; ++j) {  // K: 32 rows, 1 row (1024B) per instr
      int row = wave * 4 + j;
      const ushort_t* gp = KfB + (size_t)(s0n + row) * Dz + lane * 8;
      __builtin_amdgcn_global_load_lds(AS1(gp), AS3(&sK[bsel][row][0]), 16, 0, 0);
    }
#pragma unroll
    for (int j = 0; j < 4; ++j) {  // V: 512 d-rows of 64B, 16 rows per instr
      int dbase = wave * 64 + j * 16;
      int d = dbase + (lane >> 2);
      const ushort_t* gp = VtB + (size_t)d * Sz + s0n + vql * 8;
      __builtin_amdgcn_global_load_lds(AS1(gp), AS3(&sV[bsel][dbase][0]), 16, 0, 0);
    }
  };
  auto load_mask = [&](int s0n) -> unsigned {
    return MpB[(size_t)l16 * (Sz / 32) + (s0n >> 5)];
  };

  // ---- prologue: DMA(0), mask(0), Q frags, DMA(1) ----
  issue_tile(sbeg, 0);
  unsigned msk_cur = load_mask(sbeg);

  f16x8 qa[16];  // Q rows qw+l16, fp16; B-operand of swapped QK
  {
    const float* qrow = Qb + (size_t)l16 * Dz;
#pragma unroll
    for (int kk = 0; kk < 16; ++kk) {
      const float4 a = *(const float4*)(qrow + kk * 32 + quad * 8);
      const float4 c = *(const float4*)(qrow + kk * 32 + quad * 8 + 4);
      f16x8 h;
      h[0] = (_Float16)a.x; h[1] = (_Float16)a.y;
      h[2] = (_Float16)a.z; h[3] = (_Float16)a.w;
      h[4] = (_Float16)c.x; h[5] = (_Float16)c.y;
      h[6] = (_Float16)c.z; h[7] = (_Float16)c.w;
      qa[kk] = h;
    }
  }
  if (NTt > 1) issue_tile(sbeg + TS, 1);
  DRAIN_ALL();       // each wave retires its own DMA portion...
  __syncthreads();   // ...then barrier => whole tile 0 (and 1) visible

  float m_ln = -1e30f, l_ln = 0.0f;  // running stats for q = qw + l16
  f32x4 oacc[32];
#pragma unroll
  for (int nt = 0; nt < 32; ++nt) oacc[nt] = (f32x4){0.f, 0.f, 0.f, 0.f};

  const ushort_t* vbase0 = &sV[0][0][0] + (size_t)l16 * TS + vcol;
  const ushort_t* vbase1 = &sV[1][0][0] + (size_t)l16 * TS + vcol;

  for (int i = 0; i < NTt; ++i) {
    const int buf = i & 1;
    if (i) {
      DRAIN_ALL();      // retire DMA(i) (flight = full tile i-1 compute)
      __syncthreads();  // all waves done reading buf^1 (tile i-1's buffer)
      if (i + 1 < NTt) issue_tile(sbeg + (i + 1) * TS, buf ^ 1);
    }
    unsigned msk_nxt = (i + 1 < NTt) ? load_mask(sbeg + (i + 1) * TS) : 0u;

    // ---- QK: S^T = K·Q^T, 4 independent chains of 8 ----
    f32x4 a00 = (f32x4){0.f,0.f,0.f,0.f}, a01 = (f32x4){0.f,0.f,0.f,0.f};
    f32x4 a10 = (f32x4){0.f,0.f,0.f,0.f}, a11 = (f32x4){0.f,0.f,0.f,0.f};
    {
      const ushort_t* kh0 = &sK[buf][l16][quad * 8];
      const ushort_t* kh1 = &sK[buf][16 + l16][quad * 8];
#pragma unroll
      for (int kk = 0; kk < 16; kk += 2) {
        f16x8 k00 = *(const f16x8*)(kh0 + kk * 32);
        f16x8 k10 = *(const f16x8*)(kh1 + kk * 32);
        f16x8 k01 = *(const f16x8*)(kh0 + kk * 32 + 32);
        f16x8 k11 = *(const f16x8*)(kh1 + kk * 32 + 32);
        a00 = __builtin_amdgcn_mfma_f32_16x16x32_f16(k00, qa[kk], a00, 0, 0, 0);
        a10 = __builtin_amdgcn_mfma_f32_16x16x32_f16(k10, qa[kk], a10, 0, 0, 0);
        a01 = __builtin_amdgcn_mfma_f32_16x16x32_f16(k01, qa[kk+1], a01, 0, 0, 0);
        a11 = __builtin_amdgcn_mfma_f32_16x16x32_f16(k11, qa[kk+1], a11, 0, 0, 0);
      }
    }
    f32x4 s0v, s1v;
#pragma unroll
    for (int r = 0; r < 4; ++r) { s0v[r] = a00[r] + a01[r]; s1v[r] = a10[r] + a11[r]; }

    // ---- intra-wave masked softmax; lane holds s = quad*4+r (+16), q = l16
    const unsigned mb = msk_cur;
    float se0[4], se1[4];
#pragma unroll
    for (int r = 0; r < 4; ++r) {
      se0[r] = ((mb >> (quad * 4 + r)) & 1u)      ? s0v[r] : -1e30f;
      se1[r] = ((mb >> (16 + quad * 4 + r)) & 1u) ? s1v[r] : -1e30f;
    }
    float rmax = fmaxf(fmaxf(fmaxf(se0[0], se0[1]), fmaxf(se0[2], se0[3])),
                       fmaxf(fmaxf(se1[0], se1[1]), fmaxf(se1[2], se1[3])));
    rmax = fmaxf(rmax, __shfl_xor(rmax, 16));
    rmax = fmaxf(rmax, __shfl_xor(rmax, 32));

    ushort_t pb0[4], pb1[4];
    float rsum = 0.f;
#pragma unroll
    for (int r = 0; r < 4; ++r) {
      float p0 = ((mb >> (quad * 4 + r)) & 1u)      ? __expf(se0[r] - rmax) : 0.f;
      float p1 = ((mb >> (16 + quad * 4 + r)) & 1u) ? __expf(se1[r] - rmax) : 0.f;
      pb0[r] = f2h(p0); pb1[r] = f2h(p1);
      rsum += h2f(pb0[r]) + h2f(pb1[r]);
    }
    {  // two 8B writes into this wave's private sP strip
      uint2 w0, w1;
      w0.x = (unsigned)pb0[0] | ((unsigned)pb0[1] << 16);
      w0.y = (unsigned)pb0[2] | ((unsigned)pb0[3] << 16);
      w1.x = (unsigned)pb1[0] | ((unsigned)pb1[1] << 16);
      w1.y = (unsigned)pb1[2] | ((unsigned)pb1[3] << 16);
      *(uint2*)(&sP[wave][l16][quad * 4]) = w0;
      *(uint2*)(&sP[wave][l16][16 + quad * 4]) = w1;
    }
    rsum += __shfl_xor(rsum, 16);
    rsum += __shfl_xor(rsum, 32);

    // ---- register stats update (q = l16) ----
    float m_new = fmaxf(m_ln, rmax);
    float scl   = __expf(rmax - m_new);   // scales this tile's P
    float al_ln = __expf(m_ln - m_new);   // rescales old l / oacc
    bool  grw   = m_new > m_ln;
    l_ln = al_ln * l_ln + scl * rsum;
    m_ln = m_new;

    // ---- gather P A-frag (intra-wave LDS, wave-synchronous) + scale ----
    f16x8 praw = *(const f16x8*)(&sP[wave][l16][quad * 8]);
    f16x8 pa;
    {
      _Float16 sh16 = (_Float16)scl;
#pragma unroll
      for (int j = 0; j < 8; ++j) pa[j] = praw[j] * sh16;  // v_pk_mul_f16
    }

    if (__any((int)grw)) {  // EXACT skip: all alphas == 1 when no max grew
      float al[4];
#pragma unroll
      for (int r = 0; r < 4; ++r) al[r] = __shfl(al_ln, quad * 4 + r);
#pragma unroll
      for (int nt = 0; nt < 32; ++nt)
#pragma unroll
        for (int r = 0; r < 4; ++r) oacc[nt][r] *= al[r];
    }

    // ---- PV: 32 independent MFMAs, swizzled sV reads ----
    const ushort_t* vb_ = buf ? vbase1 : vbase0;
#pragma unroll
    for (int nt = 0; nt < 32; ++nt) {
      f16x8 vb = *(const f16x8*)(vb_ + nt * 512);
      oacc[nt] = __builtin_amdgcn_mfma_f32_16x16x32_f16(pa, vb, oacc[nt], 0, 0, 0);
    }

    msk_cur = msk_nxt;
  }

  // ---- epilogue: no barrier needed (all state register/private) ----
  const size_t rbase = (size_t)(b * SPLIT + sh) * NQz + q0 + wave * 16;
#pragma unroll
  for (int nt = 0; nt < 32; ++nt) {
#pragma unroll
    for (int r = 0; r < 4; ++r) {
      Opart[(rbase + quad * 4 + r) * Dz + nt * 16 + l16] = f2h(oacc[nt][r]);
    }
  }
  if (quad == 0) {
    Mpart[rbase + l16] = m_ln;
    Lpart[rbase + l16] = l_ln;
  }
}

// ---------------- combine the SPLIT S-parts (fp16 Opart) ----------------
template <int SPLIT>
__global__ __launch_bounds__(256)
void combine(const ushort_t* __restrict__ Opart, const float* __restrict__ Mpart,
             const float* __restrict__ Lpart, float* __restrict__ Out) {
  int gid = blockIdx.x * 256 + threadIdx.x;
  int row = gid >> 7;
  int b   = row >> 10;
  int q   = row & 1023;
  int c   = (gid & 127) * 4;
  float mv[SPLIT], lv[SPLIT];
  float m = -1e30f;
#pragma unroll
  for (int p = 0; p < SPLIT; ++p) {
    size_t ip = (size_t)(b * SPLIT + p) * NQz + q;
    mv[p] = Mpart[ip];
    lv[p] = Lpart[ip];
    m = fmaxf(m, mv[p]);
  }
  float w[SPLIT], denom = 0.f;
#pragma unroll
  for (int p = 0; p < SPLIT; ++p) {
    w[p] = __expf(mv[p] - m);
    denom += w[p] * lv[p];
  }
  float inv = 1.0f / denom;
  float4 o = {0.f, 0.f, 0.f, 0.f};
#pragma unroll
  for (int p = 0; p < SPLIT; ++p) {
    size_t ip = (size_t)(b * SPLIT + p) * NQz + q;
    const ushort_t* op = Opart + ip * Dz + c;
    uint2 raw = *(const uint2*)op;  // 4 halves
    o.x += w[p] * h2f((ushort_t)(raw.x & 0xffff));
    o.y += w[p] * h2f((ushort_t)(raw.x >> 16));
    o.z += w[p] * h2f((ushort_t)(raw.y & 0xffff));
    o.w += w[p] * h2f((ushort_t)(raw.y >> 16));
  }
  o.x *= inv; o.y *= inv; o.z *= inv; o.w *= inv;
  *(float4*)(Out + ((size_t)b * NQz + q) * Dz + c) = o;
}

extern "C" void kernel_launch(void* const* d_in, const int* in_sizes, int n_in,
                              void* d_out, int out_size, void* d_ws, size_t ws_size,
                              hipStream_t stream) {
  const float* Q = (const float*)d_in[0];
  const float* K = (const float*)d_in[1];
  const float* V = (const float*)d_in[2];
  const int*   M = (const int*)d_in[3];
  float* O = (float*)d_out;

  const size_t NKV   = (size_t)Bz * Sz * Dz;        // f16 elems per tensor
  const size_t maskW = (size_t)Bz * NQz * (Sz / 32);

  // Split-independent layout: Kf | Vt | Mp | Opart(fp16) | Mpart | Lpart
  ushort_t* Kf = (ushort_t*)d_ws;
  ushort_t* Vt = Kf + NKV;
  unsigned* Mp = (unsigned*)(Vt + NKV);
  ushort_t* Opart = (ushort_t*)(Mp + maskW);

  auto need_bytes = [&](int S) -> size_t {
    return NKV * 2 * 2 + maskW * 4
         + (size_t)Bz * S * NQz * Dz * 2       // Opart fp16
         + (size_t)Bz * S * NQz * 4 * 2;       // Mpart + Lpart
  };

  prep<<<dim3(28672), dim3(256), 0, stream>>>(K, V, M, Kf, Vt, Mp);

  if (ws_size >= need_bytes(4)) {
    constexpr int S = 4;
    float* Mpart = (float*)(Opart + (size_t)Bz * S * NQz * Dz);
    float* Lpart = Mpart + (size_t)Bz * S * NQz;
    attn_flash<S><<<dim3(8 * (NQz / QTT) * S), dim3(512), 0, stream>>>(
        Q, Mp, Kf, Vt, Opart, Mpart, Lpart);
    combine<S><<<dim3(4096), dim3(256), 0, stream>>>(Opart, Mpart, Lpart, O);
  } else {
    constexpr int S = 2;
    float* Mpart = (float*)(Opart + (size_t)Bz * S * NQz * Dz);
    float* Lpart = Mpart + (size_t)Bz * S * NQz;
    attn_flash<S><<<dim3(8 * (NQz / QTT) * S), dim3(512), 0, stream>>>(
        Q, Mp, Kf, Vt, Opart, Mpart, Lpart);
    combine<S><<<dim3(4096), dim3(256), 0, stream>>>(Opart, Mpart, Lpart, O);
  }
}